// Round 4
// baseline (1249.080 us; speedup 1.0000x reference)
//
#include <hip/hip_runtime.h>
#include <hip/hip_bf16.h>

typedef __bf16 bf16_t;
typedef bf16_t bf16x8 __attribute__((ext_vector_type(8)));
typedef bf16_t bf16x4 __attribute__((ext_vector_type(4)));
typedef float f32x4 __attribute__((ext_vector_type(4)));

#define DEV static __device__ __forceinline__

constexpr int kB = 2, kS = 2048, kD = 1024, kH = 16;
constexpr int kRows = kB * kS;  // 4096
constexpr int kDff = 4096;
constexpr float kLnEps = 1e-5f;
constexpr float kL2E = 1.4426950408889634f;

DEV f32x4 mfma16(bf16x8 a, bf16x8 b, f32x4 c) {
  return __builtin_amdgcn_mfma_f32_16x16x32_bf16(a, b, c, 0, 0, 0);
}
DEV float ex2(float x) { return __builtin_amdgcn_exp2f(x); }
DEV float lg2(float x) { return __builtin_amdgcn_logf(x); }

// ---------------- LayerNorm: one wave per row, f32 in -> bf16 out ----------
__global__ __launch_bounds__(256) void k_ln(const float* __restrict__ in,
                                            const float* __restrict__ gw,
                                            const float* __restrict__ bw,
                                            bf16_t* __restrict__ out) {
  const int wv = threadIdx.x >> 6, ln = threadIdx.x & 63;
  const long row = (long)blockIdx.x * 4 + wv;
  const float* rp = in + row * kD;
  float4 v[4];
#pragma unroll
  for (int j = 0; j < 4; ++j) v[j] = reinterpret_cast<const float4*>(rp)[ln + 64 * j];
  float s = 0.f, s2 = 0.f;
#pragma unroll
  for (int j = 0; j < 4; ++j) {
    s += v[j].x + v[j].y + v[j].z + v[j].w;
    s2 += v[j].x * v[j].x + v[j].y * v[j].y + v[j].z * v[j].z + v[j].w * v[j].w;
  }
#pragma unroll
  for (int m = 1; m < 64; m <<= 1) { s += __shfl_xor(s, m); s2 += __shfl_xor(s2, m); }
  const float mean = s * (1.f / kD);
  const float var = s2 * (1.f / kD) - mean * mean;
  const float rstd = rsqrtf(var + kLnEps);
  bf16_t* op = out + row * kD;
#pragma unroll
  for (int j = 0; j < 4; ++j) {
    const int c4 = ln + 64 * j;
    float4 gv = reinterpret_cast<const float4*>(gw)[c4];
    float4 bv = reinterpret_cast<const float4*>(bw)[c4];
    bf16x4 o;
    o[0] = (bf16_t)((v[j].x - mean) * rstd * gv.x + bv.x);
    o[1] = (bf16_t)((v[j].y - mean) * rstd * gv.y + bv.y);
    o[2] = (bf16_t)((v[j].z - mean) * rstd * gv.z + bv.z);
    o[3] = (bf16_t)((v[j].w - mean) * rstd * gv.w + bv.w);
    *reinterpret_cast<bf16x4*>(op + c4 * 4) = o;
  }
}

// ------------- transpose f32 [K][N] -> bf16 [N][K] (64x64 tiles) ----------
__global__ __launch_bounds__(256) void k_transpose(const float* __restrict__ in,
                                                   bf16_t* __restrict__ out,
                                                   int K, int N, long inZ, long outZ) {
  in += (long)blockIdx.z * inZ;
  out += (long)blockIdx.z * outZ;
  __shared__ float t[64][65];
  const int k0 = blockIdx.x * 64, n0 = blockIdx.y * 64;
  const int tid = threadIdx.x;
  const int r = tid >> 2, cg = (tid & 3) * 16;
#pragma unroll
  for (int q = 0; q < 4; ++q) {
    float4 v = reinterpret_cast<const float4*>(in + (long)(k0 + r) * N + n0 + cg)[q];
    t[r][cg + q * 4 + 0] = v.x;
    t[r][cg + q * 4 + 1] = v.y;
    t[r][cg + q * 4 + 2] = v.z;
    t[r][cg + q * 4 + 3] = v.w;
  }
  __syncthreads();
  union { ushort u[16]; uint4 q[2]; } ob;
#pragma unroll
  for (int i = 0; i < 16; ++i) {
    bf16_t hh = (bf16_t)t[cg + i][r];
    ob.u[i] = __builtin_bit_cast(ushort, hh);
  }
  uint4* dst = reinterpret_cast<uint4*>(out + (long)(n0 + r) * K + k0 + cg);
  dst[0] = ob.q[0];
  dst[1] = ob.q[1];
}

// ---------------- GEMM: C[M,N] = A[M,K] * Bt[N,K]^T, bf16 MFMA -------------
// EPI: 0 = +qkv-bias -> bf16 ; 1 = +bias,GELU -> bf16 ; 2 = +bias+resid -> f32
template <int BM, int BN, int WM, int WN, int EPI>
__global__ __launch_bounds__(256) void k_gemm(const bf16_t* __restrict__ A,
                                              const bf16_t* __restrict__ Bt,
                                              float* __restrict__ outF,
                                              bf16_t* __restrict__ outB,
                                              const float* __restrict__ bias0,
                                              const float* __restrict__ bias1,
                                              const float* __restrict__ bias2,
                                              const float* __restrict__ resid,
                                              int M, int N, int K) {
  constexpr int MI = WM / 16, NI = WN / 16;
  constexpr int NWN = BN / WN;
  __shared__ bf16_t As[BM][40];  // +8 pad: stride 80B -> ~2-way (free) on frag reads
  __shared__ bf16_t Bs[BN][40];
  const int tid = threadIdx.x;
  const int wv = tid >> 6, ln = tid & 63;
  const int wmB = (wv / NWN) * WM, wnB = (wv % NWN) * WN;
  const int m0 = blockIdx.y * BM, n0 = blockIdx.x * BN;
  const int nk = K >> 5;
  const int lrow = ln & 15, lk8 = (ln >> 4) * 8;

  constexpr int ACH = (BM * 2 + 255) / 256;
  constexpr int BCH = (BN * 2 + 255) / 256;
  uint4 pa[ACH][2], pb[BCH][2];

  auto LD = [&](int kk) {
#pragma unroll
    for (int c = 0; c < ACH; ++c) {
      int ch = tid + c * 256;
      if (ch < BM * 2) {
        const uint4* p = reinterpret_cast<const uint4*>(A + (long)(m0 + (ch >> 1)) * K + kk * 32 + (ch & 1) * 16);
        pa[c][0] = p[0];
        pa[c][1] = p[1];
      }
    }
#pragma unroll
    for (int c = 0; c < BCH; ++c) {
      int ch = tid + c * 256;
      if (ch < BN * 2) {
        const uint4* p = reinterpret_cast<const uint4*>(Bt + (long)(n0 + (ch >> 1)) * K + kk * 32 + (ch & 1) * 16);
        pb[c][0] = p[0];
        pb[c][1] = p[1];
      }
    }
  };

  LD(0);
  f32x4 acc[MI][NI] = {};
  for (int kk = 0; kk < nk; ++kk) {
    __syncthreads();
#pragma unroll
    for (int c = 0; c < ACH; ++c) {
      int ch = tid + c * 256;
      if (ch < BM * 2) {
        *reinterpret_cast<uint4*>(&As[ch >> 1][(ch & 1) * 16]) = pa[c][0];
        *reinterpret_cast<uint4*>(&As[ch >> 1][(ch & 1) * 16 + 8]) = pa[c][1];
      }
    }
#pragma unroll
    for (int c = 0; c < BCH; ++c) {
      int ch = tid + c * 256;
      if (ch < BN * 2) {
        *reinterpret_cast<uint4*>(&Bs[ch >> 1][(ch & 1) * 16]) = pb[c][0];
        *reinterpret_cast<uint4*>(&Bs[ch >> 1][(ch & 1) * 16 + 8]) = pb[c][1];
      }
    }
    __syncthreads();
    if (kk + 1 < nk) LD(kk + 1);  // prefetch next tile; latency hides under MFMA
    bf16x8 af[MI], bfr[NI];
#pragma unroll
    for (int i = 0; i < MI; ++i)
      af[i] = *reinterpret_cast<const bf16x8*>(&As[wmB + i * 16 + lrow][lk8]);
#pragma unroll
    for (int j = 0; j < NI; ++j)
      bfr[j] = *reinterpret_cast<const bf16x8*>(&Bs[wnB + j * 16 + lrow][lk8]);
#pragma unroll
    for (int i = 0; i < MI; ++i)
#pragma unroll
      for (int j = 0; j < NI; ++j) acc[i][j] = mfma16(af[i], bfr[j], acc[i][j]);
  }

  const int lr4 = (ln >> 4) * 4;
#pragma unroll
  for (int i = 0; i < MI; ++i) {
#pragma unroll
    for (int j = 0; j < NI; ++j) {
#pragma unroll
      for (int r = 0; r < 4; ++r) {
        const int m = m0 + wmB + i * 16 + lr4 + r;
        const int n = n0 + wnB + j * 16 + lrow;
        float c = acc[i][j][r];
        if constexpr (EPI == 0) {
          const float bias = (n < 1024) ? bias0[n] : (n < 2048) ? bias1[n - 1024] : bias2[n - 2048];
          outB[(long)m * N + n] = (bf16_t)(c + bias);
        } else if constexpr (EPI == 1) {
          const float xx = c + bias0[n];
          outB[(long)m * N + n] = (bf16_t)(0.5f * xx * (1.f + erff(xx * 0.70710678118654752f)));
        } else {
          const long idx = (long)m * N + n;
          outF[idx] = c + bias0[n] + resid[idx];
        }
      }
    }
  }
}

// ---------------- fused attention: 2-pass flash + attn/entropy outputs -----
// grid (S/64, H, B), 256 threads (4 waves, 16 q-rows each)
__global__ __launch_bounds__(256) void k_attn(const bf16_t* __restrict__ qkv,
                                              const float* __restrict__ x,
                                              float* __restrict__ attnO,
                                              float* __restrict__ entO,
                                              float* __restrict__ y) {
  __shared__ bf16_t Qs[64][72];
  __shared__ bf16_t Ks[128][72];
  __shared__ bf16_t Vts[64][136];      // V transposed: [d][kc]
  __shared__ bf16_t Ps[4][16][136];    // per-wave P tile [qrow][kc]

  const int tid = threadIdx.x, wv = tid >> 6, ln = tid & 63;
  const int q0 = blockIdx.x * 64, h = blockIdx.y, b = blockIdx.z;
  const long rowbase = (long)b * kS;
  const int qcol = h * 64, kcol = kD + h * 64, vcol = 2 * kD + h * 64;
  const int lrow = ln & 15, lk8 = (ln >> 4) * 8;

  {  // stage Q once
    const int r = tid >> 2, cg = (tid & 3) * 16;
    const uint4* p = reinterpret_cast<const uint4*>(qkv + (rowbase + q0 + r) * 3072 + qcol + cg);
    uint4 v0 = p[0], v1 = p[1];
    *reinterpret_cast<uint4*>(&Qs[r][cg]) = v0;
    *reinterpret_cast<uint4*>(&Qs[r][cg + 8]) = v1;
  }
  __syncthreads();
  bf16x8 qf[2];
  qf[0] = *reinterpret_cast<const bf16x8*>(&Qs[wv * 16 + lrow][lk8]);
  qf[1] = *reinterpret_cast<const bf16x8*>(&Qs[wv * 16 + lrow][32 + lk8]);

  const int krow = tid >> 1, kc4 = (tid & 1) * 32;
  uint4 kr[4], vr[4];
  auto LDK = [&](int kt) {
    const uint4* p = reinterpret_cast<const uint4*>(qkv + (rowbase + kt * 128 + krow) * 3072 + kcol + kc4);
    kr[0] = p[0]; kr[1] = p[1]; kr[2] = p[2]; kr[3] = p[3];
  };
  auto LDV = [&](int kt) {
    const uint4* p = reinterpret_cast<const uint4*>(qkv + (rowbase + kt * 128 + krow) * 3072 + vcol + kc4);
    vr[0] = p[0]; vr[1] = p[1]; vr[2] = p[2]; vr[3] = p[3];
  };

  float mrow[4] = {-1e30f, -1e30f, -1e30f, -1e30f};
  float lsum[4] = {0.f, 0.f, 0.f, 0.f}, ssum[4] = {0.f, 0.f, 0.f, 0.f};

  // ---- pass 1: running max / sumexp / sum p*s ----
  LDK(0);
  for (int kt = 0; kt < 16; ++kt) {
    __syncthreads();
    *reinterpret_cast<uint4*>(&Ks[krow][kc4]) = kr[0];
    *reinterpret_cast<uint4*>(&Ks[krow][kc4 + 8]) = kr[1];
    *reinterpret_cast<uint4*>(&Ks[krow][kc4 + 16]) = kr[2];
    *reinterpret_cast<uint4*>(&Ks[krow][kc4 + 24]) = kr[3];
    __syncthreads();
    if (kt + 1 < 16) LDK(kt + 1);
    f32x4 sc[8] = {};
#pragma unroll
    for (int ds = 0; ds < 2; ++ds)
#pragma unroll
      for (int kf = 0; kf < 8; ++kf) {
        bf16x8 bk = *reinterpret_cast<const bf16x8*>(&Ks[kf * 16 + lrow][ds * 32 + lk8]);
        sc[kf] = mfma16(qf[ds], bk, sc[kf]);
      }
    float tm[4] = {-1e30f, -1e30f, -1e30f, -1e30f};
#pragma unroll
    for (int kf = 0; kf < 8; ++kf)
#pragma unroll
      for (int r = 0; r < 4; ++r) tm[r] = fmaxf(tm[r], sc[kf][r]);
#pragma unroll
    for (int mk = 1; mk < 16; mk <<= 1)
#pragma unroll
      for (int r = 0; r < 4; ++r) tm[r] = fmaxf(tm[r], __shfl_xor(tm[r], mk));
#pragma unroll
    for (int r = 0; r < 4; ++r) {
      const float mn = fmaxf(mrow[r], tm[r] * 0.125f);
      const float f = ex2((mrow[r] - mn) * kL2E);
      lsum[r] *= f;
      ssum[r] *= f;
      mrow[r] = mn;
    }
#pragma unroll
    for (int kf = 0; kf < 8; ++kf)
#pragma unroll
      for (int r = 0; r < 4; ++r) {
        const float s = sc[kf][r] * 0.125f;
        const float p = ex2((s - mrow[r]) * kL2E);
        lsum[r] += p;
        ssum[r] += p * s;
      }
  }
#pragma unroll
  for (int mk = 1; mk < 16; mk <<= 1)
#pragma unroll
    for (int r = 0; r < 4; ++r) {
      lsum[r] += __shfl_xor(lsum[r], mk);
      ssum[r] += __shfl_xor(ssum[r], mk);
    }
  float linv[4];
#pragma unroll
  for (int r = 0; r < 4; ++r) linv[r] = 1.0f / lsum[r];
  if (lrow == 0) {  // entropy = log2(l) - log2e*(E[s]-m)
#pragma unroll
    for (int r = 0; r < 4; ++r) {
      const float Hent = lg2(lsum[r]) - kL2E * (ssum[r] * linv[r] - mrow[r]);
      entO[(long)(h * kB + b) * kS + q0 + wv * 16 + (ln >> 4) * 4 + r] = Hent;
    }
  }

  // ---- pass 2: recompute scores, emit attn weights, accumulate PV ----
  f32x4 accO[4] = {};
  LDK(0);
  LDV(0);
  for (int kt = 0; kt < 16; ++kt) {
    __syncthreads();
    *reinterpret_cast<uint4*>(&Ks[krow][kc4]) = kr[0];
    *reinterpret_cast<uint4*>(&Ks[krow][kc4 + 8]) = kr[1];
    *reinterpret_cast<uint4*>(&Ks[krow][kc4 + 16]) = kr[2];
    *reinterpret_cast<uint4*>(&Ks[krow][kc4 + 24]) = kr[3];
    {  // V transpose-scatter into LDS
      union { uint4 q[4]; ushort u[32]; } tv;
      tv.q[0] = vr[0]; tv.q[1] = vr[1]; tv.q[2] = vr[2]; tv.q[3] = vr[3];
      const int dbase = (tid & 1) * 32;
#pragma unroll
      for (int j = 0; j < 32; ++j)
        *reinterpret_cast<ushort*>(&Vts[dbase + j][krow]) = tv.u[j];
    }
    __syncthreads();
    if (kt + 1 < 16) { LDK(kt + 1); LDV(kt + 1); }
    f32x4 sc[8] = {};
#pragma unroll
    for (int ds = 0; ds < 2; ++ds)
#pragma unroll
      for (int kf = 0; kf < 8; ++kf) {
        bf16x8 bk = *reinterpret_cast<const bf16x8*>(&Ks[kf * 16 + lrow][ds * 32 + lk8]);
        sc[kf] = mfma16(qf[ds], bk, sc[kf]);
      }
    const long arow0 = (long)(h * kB + b) * kS + q0 + wv * 16;
#pragma unroll
    for (int kf = 0; kf < 8; ++kf)
#pragma unroll
      for (int r = 0; r < 4; ++r) {
        const int qr = (ln >> 4) * 4 + r;
        const float s = sc[kf][r] * 0.125f;
        const float p = ex2((s - mrow[r]) * kL2E) * linv[r];
        __builtin_nontemporal_store(p, &attnO[(arow0 + qr) * (long)kS + kt * 128 + kf * 16 + lrow]);
        Ps[wv][qr][kf * 16 + lrow] = (bf16_t)p;
      }
    __syncthreads();
#pragma unroll
    for (int ks = 0; ks < 4; ++ks) {
      bf16x8 pfr = *reinterpret_cast<const bf16x8*>(&Ps[wv][lrow][ks * 32 + lk8]);
#pragma unroll
      for (int df = 0; df < 4; ++df) {
        bf16x8 vfr = *reinterpret_cast<const bf16x8*>(&Vts[df * 16 + lrow][ks * 32 + lk8]);
        accO[df] = mfma16(pfr, vfr, accO[df]);
      }
    }
  }
  // y = concat(head_out) + x
#pragma unroll
  for (int df = 0; df < 4; ++df)
#pragma unroll
    for (int r = 0; r < 4; ++r) {
      const long row = rowbase + q0 + wv * 16 + (ln >> 4) * 4 + r;
      const int col = h * 64 + df * 16 + lrow;
      y[row * kD + col] = accO[df][r] + x[row * kD + col];
    }
}

extern "C" void kernel_launch(void* const* d_in, const int* in_sizes, int n_in,
                              void* d_out, int out_size, void* d_ws, size_t ws_size,
                              hipStream_t stream) {
  const float* x    = (const float*)d_in[0];
  const float* Wq   = (const float*)d_in[1];
  const float* bq   = (const float*)d_in[2];
  const float* Wk   = (const float*)d_in[3];
  const float* bk   = (const float*)d_in[4];
  const float* Wv   = (const float*)d_in[5];
  const float* bv   = (const float*)d_in[6];
  const float* ln1g = (const float*)d_in[7];
  const float* ln1b = (const float*)d_in[8];
  const float* ln2g = (const float*)d_in[9];
  const float* ln2b = (const float*)d_in[10];
  const float* W1   = (const float*)d_in[11];
  const float* b1   = (const float*)d_in[12];
  const float* W2   = (const float*)d_in[13];
  const float* b2   = (const float*)d_in[14];

  float* outMain = (float*)d_out;                       // [2,2048,1024]
  float* attnO   = outMain + (long)kRows * kD;          // [16,2,2048,2048]
  float* entO    = attnO + (long)kH * kB * kS * kS;     // [16,2,2048]

  // Scratch plan (peak d_ws = 62 MB):
  //  - h1/h2 (8 MB each) live inside d_out's outMain region (16 MB): h1 dead
  //    after QKV GEMM, h2 dead after MLP1, and MLP2's epilogue overwrites
  //    every outMain element afterwards. Stream ordering makes this safe.
  //  - mid (32 MB) aliases dead qkv (24 MB) region in d_ws.
  bf16_t* h1 = (bf16_t*)outMain;                        // 8 MB scratch in d_out
  bf16_t* h2 = (bf16_t*)(outMain + (long)kRows * kD / 2);  // second 8 MB half

  char* ws = (char*)d_ws;
  bf16_t* wqkvt = (bf16_t*)ws; ws += (long)3072 * 1024 * 2;   //  6 MB (persist)
  bf16_t* w1t   = (bf16_t*)ws; ws += (long)4096 * 1024 * 2;   //  8 MB (persist)
  bf16_t* w2t   = (bf16_t*)ws; ws += (long)1024 * 4096 * 2;   //  8 MB (persist)
  float*  yb    = (float*)ws;  ws += (long)kRows * kD * 4;    // 16 MB (persist attn->MLP2)
  char* regionA = ws;                                         // 32 MB shared region
  bf16_t* qkv   = (bf16_t*)regionA;                           // 24 MB (dead after attn)
  bf16_t* mid   = (bf16_t*)regionA;                           // 32 MB (aliases qkv)

  // weight conversion/transpose to bf16 [N][K]
  hipLaunchKernelGGL(k_transpose, dim3(16, 1, 16), dim3(256), 0, stream, Wq, wqkvt,             1024, 64, (long)65536, (long)65536);
  hipLaunchKernelGGL(k_transpose, dim3(16, 1, 16), dim3(256), 0, stream, Wk, wqkvt + 1024*1024, 1024, 64, (long)65536, (long)65536);
  hipLaunchKernelGGL(k_transpose, dim3(16, 1, 16), dim3(256), 0, stream, Wv, wqkvt + 2048*1024, 1024, 64, (long)65536, (long)65536);
  hipLaunchKernelGGL(k_transpose, dim3(16, 64, 1), dim3(256), 0, stream, W1, w1t, 1024, 4096, 0L, 0L);
  hipLaunchKernelGGL(k_transpose, dim3(64, 16, 1), dim3(256), 0, stream, W2, w2t, 4096, 1024, 0L, 0L);
  // LN1
  hipLaunchKernelGGL(k_ln, dim3(kRows / 4), dim3(256), 0, stream, x, ln1g, ln1b, h1);
  // fused QKV projection
  hipLaunchKernelGGL((k_gemm<128, 128, 64, 64, 0>), dim3(3072 / 128, kRows / 128), dim3(256), 0, stream,
                     h1, wqkvt, nullptr, qkv, bq, bk, bv, nullptr, kRows, 3072, 1024);
  // attention (+ attn weights, entropy, y = cat + x)
  hipLaunchKernelGGL(k_attn, dim3(kS / 64, kH, kB), dim3(256), 0, stream, qkv, x, attnO, entO, yb);
  // LN2
  hipLaunchKernelGGL(k_ln, dim3(kRows / 4), dim3(256), 0, stream, yb, ln2g, ln2b, h2);
  // MLP
  hipLaunchKernelGGL((k_gemm<128, 128, 64, 64, 1>), dim3(kDff / 128, kRows / 128), dim3(256), 0, stream,
                     h2, w1t, nullptr, mid, b1, nullptr, nullptr, nullptr, kRows, kDff, 1024);
  hipLaunchKernelGGL((k_gemm<64, 128, 64, 32, 2>), dim3(kD / 128, kRows / 64), dim3(256), 0, stream,
                     mid, w2t, outMain, nullptr, b2, nullptr, nullptr, yb, kRows, kD, 4096);
}

// Round 5
// 929.978 us; speedup vs baseline: 1.3431x; 1.3431x over previous
//
#include <hip/hip_runtime.h>
#include <hip/hip_bf16.h>

typedef __bf16 bf16_t;
typedef bf16_t bf16x8 __attribute__((ext_vector_type(8)));
typedef bf16_t bf16x4 __attribute__((ext_vector_type(4)));
typedef float f32x4 __attribute__((ext_vector_type(4)));
typedef unsigned short us4 __attribute__((ext_vector_type(4)));
typedef unsigned int u32;

#define DEV static __device__ __forceinline__

constexpr int kB = 2, kS = 2048, kD = 1024, kH = 16;
constexpr int kRows = kB * kS;  // 4096
constexpr int kDff = 4096;
constexpr float kLnEps = 1e-5f;
constexpr float kQscale = 0.18033688011112042f;  // 0.125 * log2(e)

DEV f32x4 mfma16(bf16x8 a, bf16x8 b, f32x4 c) {
  return __builtin_amdgcn_mfma_f32_16x16x32_bf16(a, b, c, 0, 0, 0);
}
DEV float ex2(float x) { return __builtin_amdgcn_exp2f(x); }
DEV float lg2(float x) { return __builtin_amdgcn_logf(x); }
// async global->LDS, 16B per lane; LDS dest = wave-uniform base + lane*16
DEV void gload16(const bf16_t* g, bf16_t* l) {
  __builtin_amdgcn_global_load_lds(
      (const __attribute__((address_space(1))) u32*)g,
      (__attribute__((address_space(3))) u32*)l, 16, 0, 0);
}

// ---------------- LayerNorm: one wave per row, f32 in -> bf16 out ----------
__global__ __launch_bounds__(256) void k_ln(const float* __restrict__ in,
                                            const float* __restrict__ gw,
                                            const float* __restrict__ bw,
                                            bf16_t* __restrict__ out) {
  const int wv = threadIdx.x >> 6, ln = threadIdx.x & 63;
  const long row = (long)blockIdx.x * 4 + wv;
  const float* rp = in + row * kD;
  float4 v[4];
#pragma unroll
  for (int j = 0; j < 4; ++j) v[j] = reinterpret_cast<const float4*>(rp)[ln + 64 * j];
  float s = 0.f, s2 = 0.f;
#pragma unroll
  for (int j = 0; j < 4; ++j) {
    s += v[j].x + v[j].y + v[j].z + v[j].w;
    s2 += v[j].x * v[j].x + v[j].y * v[j].y + v[j].z * v[j].z + v[j].w * v[j].w;
  }
#pragma unroll
  for (int m = 1; m < 64; m <<= 1) { s += __shfl_xor(s, m); s2 += __shfl_xor(s2, m); }
  const float mean = s * (1.f / kD);
  const float var = s2 * (1.f / kD) - mean * mean;
  const float rstd = rsqrtf(var + kLnEps);
  bf16_t* op = out + row * kD;
#pragma unroll
  for (int j = 0; j < 4; ++j) {
    const int c4 = ln + 64 * j;
    float4 gv = reinterpret_cast<const float4*>(gw)[c4];
    float4 bv = reinterpret_cast<const float4*>(bw)[c4];
    bf16x4 o;
    o[0] = (bf16_t)((v[j].x - mean) * rstd * gv.x + bv.x);
    o[1] = (bf16_t)((v[j].y - mean) * rstd * gv.y + bv.y);
    o[2] = (bf16_t)((v[j].z - mean) * rstd * gv.z + bv.z);
    o[3] = (bf16_t)((v[j].w - mean) * rstd * gv.w + bv.w);
    *reinterpret_cast<bf16x4*>(op + c4 * 4) = o;
  }
}

// ------------- transpose f32 [K][N] -> bf16 [N][K] (64x64 tiles) ----------
__global__ __launch_bounds__(256) void k_transpose(const float* __restrict__ in,
                                                   bf16_t* __restrict__ out,
                                                   int K, int N, long inZ, long outZ) {
  in += (long)blockIdx.z * inZ;
  out += (long)blockIdx.z * outZ;
  __shared__ float t[64][65];
  const int k0 = blockIdx.x * 64, n0 = blockIdx.y * 64;
  const int tid = threadIdx.x;
  const int r = tid >> 2, cg = (tid & 3) * 16;
#pragma unroll
  for (int q = 0; q < 4; ++q) {
    float4 v = reinterpret_cast<const float4*>(in + (long)(k0 + r) * N + n0 + cg)[q];
    t[r][cg + q * 4 + 0] = v.x;
    t[r][cg + q * 4 + 1] = v.y;
    t[r][cg + q * 4 + 2] = v.z;
    t[r][cg + q * 4 + 3] = v.w;
  }
  __syncthreads();
  union { ushort u[16]; uint4 q[2]; } ob;
#pragma unroll
  for (int i = 0; i < 16; ++i) {
    bf16_t hh = (bf16_t)t[cg + i][r];
    ob.u[i] = __builtin_bit_cast(ushort, hh);
  }
  uint4* dst = reinterpret_cast<uint4*>(out + (long)(n0 + r) * K + k0 + cg);
  dst[0] = ob.q[0];
  dst[1] = ob.q[1];
}

// ------- GEMM: C[M,N] = A[M,K]*Bt[N,K]^T, global_load_lds + LDS dbuf -------
// EPI: 0 = +qkv-bias -> bf16 ; 1 = +bias,GELU -> bf16 ; 2 = +bias+resid -> f32
template <int BM, int BN, int WM, int WN, int EPI>
__global__ __launch_bounds__(256, 3) void k_gemm(const bf16_t* __restrict__ A,
                                                 const bf16_t* __restrict__ Bt,
                                                 float* __restrict__ outF,
                                                 bf16_t* __restrict__ outB,
                                                 const float* __restrict__ bias0,
                                                 const float* __restrict__ bias1,
                                                 const float* __restrict__ bias2,
                                                 const float* __restrict__ resid,
                                                 int M, int N, int K) {
  constexpr int MI = WM / 16, NI = WN / 16;
  constexpr int NWN = BN / WN;
  constexpr int IPA = BM / 64, IPB = BN / 64;  // gload16 instrs per wave
  __shared__ bf16_t As[2][BM][32];  // linear (m97): gload_lds needs contiguous dest
  __shared__ bf16_t Bs[2][BN][32];
  const int tid = threadIdx.x;
  const int wv = tid >> 6, ln = tid & 63;
  const int wmB = (wv / NWN) * WM, wnB = (wv % NWN) * WN;
  const int m0 = blockIdx.y * BM, n0 = blockIdx.x * BN;
  const int nk = K >> 5;
  const int lrow = ln & 15, lk8 = (ln >> 4) * 8;
  const int gr = ln >> 2, gc = (ln & 3) * 8;  // lane's row/col within a 1KB chunk

  auto STAGE = [&](int kk, int buf) {
#pragma unroll
    for (int i = 0; i < IPA; ++i) {
      const int ch = wv * IPA + i;  // wave-uniform
      gload16(A + (long)(m0 + ch * 16 + gr) * K + kk * 32 + gc, &As[buf][ch * 16][0]);
    }
#pragma unroll
    for (int i = 0; i < IPB; ++i) {
      const int ch = wv * IPB + i;
      gload16(Bt + (long)(n0 + ch * 16 + gr) * K + kk * 32 + gc, &Bs[buf][ch * 16][0]);
    }
  };

  f32x4 acc[MI][NI] = {};
  STAGE(0, 0);
  __syncthreads();  // compiler drains vmcnt before barrier -> tile 0 ready
  for (int kk = 0; kk < nk; ++kk) {
    const int cur = kk & 1;
    if (kk + 1 < nk) STAGE(kk + 1, cur ^ 1);  // async into other buffer
    bf16x8 af[MI], bfr[NI];
#pragma unroll
    for (int i = 0; i < MI; ++i)
      af[i] = *reinterpret_cast<const bf16x8*>(&As[cur][wmB + i * 16 + lrow][lk8]);
#pragma unroll
    for (int j = 0; j < NI; ++j)
      bfr[j] = *reinterpret_cast<const bf16x8*>(&Bs[cur][wnB + j * 16 + lrow][lk8]);
    __builtin_amdgcn_s_setprio(1);
#pragma unroll
    for (int i = 0; i < MI; ++i)
#pragma unroll
      for (int j = 0; j < NI; ++j) acc[i][j] = mfma16(af[i], bfr[j], acc[i][j]);
    __builtin_amdgcn_s_setprio(0);
    __syncthreads();  // drains next-tile loads + protects buffers
  }

  const int lr4 = (ln >> 4) * 4;
#pragma unroll
  for (int i = 0; i < MI; ++i) {
#pragma unroll
    for (int j = 0; j < NI; ++j) {
#pragma unroll
      for (int r = 0; r < 4; ++r) {
        const int m = m0 + wmB + i * 16 + lr4 + r;
        const int n = n0 + wnB + j * 16 + lrow;
        float c = acc[i][j][r];
        if constexpr (EPI == 0) {
          const float bias = (n < 1024) ? bias0[n] : (n < 2048) ? bias1[n - 1024] : bias2[n - 2048];
          outB[(long)m * N + n] = (bf16_t)(c + bias);
        } else if constexpr (EPI == 1) {
          const float xx = c + bias0[n];
          outB[(long)m * N + n] = (bf16_t)(0.5f * xx * (1.f + erff(xx * 0.70710678118654752f)));
        } else {
          const long idx = (long)m * N + n;
          outF[idx] = c + bias0[n] + resid[idx];
        }
      }
    }
  }
}

// ---------------- fused attention: 2-pass flash + attn/entropy outputs -----
// grid (S/64, H, B), 256 threads (4 waves, 16 q-rows each)
// Q pre-scaled by 0.125*log2e so softmax is ex2(sc - m) directly.
__global__ __launch_bounds__(256, 3) void k_attn(const bf16_t* __restrict__ qkv,
                                                 const float* __restrict__ x,
                                                 float* __restrict__ attnO,
                                                 float* __restrict__ entO,
                                                 float* __restrict__ y) {
  __shared__ bf16_t Ks[128][72];
  __shared__ bf16_t Vts[64][136];      // V transposed: [d][kc]
  __shared__ union {                   // Qs dead after qf regs loaded -> alias Ps
    bf16_t Qs[64][72];
    bf16_t Ps[4][16][136];             // per-wave P tile [qrow][kc]
  } QP;

  const int tid = threadIdx.x, wv = tid >> 6, ln = tid & 63;
  const int q0 = blockIdx.x * 64, h = blockIdx.y, b = blockIdx.z;
  const long rowbase = (long)b * kS;
  const int qcol = h * 64, kcol = kD + h * 64, vcol = 2 * kD + h * 64;
  const int lrow = ln & 15, lk8 = (ln >> 4) * 8;

  {  // stage Q once
    const int r = tid >> 2, cg = (tid & 3) * 16;
    const uint4* p = reinterpret_cast<const uint4*>(qkv + (rowbase + q0 + r) * 3072 + qcol + cg);
    uint4 v0 = p[0], v1 = p[1];
    *reinterpret_cast<uint4*>(&QP.Qs[r][cg]) = v0;
    *reinterpret_cast<uint4*>(&QP.Qs[r][cg + 8]) = v1;
  }
  __syncthreads();
  bf16x8 qf[2];
  qf[0] = *reinterpret_cast<const bf16x8*>(&QP.Qs[wv * 16 + lrow][lk8]);
  qf[1] = *reinterpret_cast<const bf16x8*>(&QP.Qs[wv * 16 + lrow][32 + lk8]);
#pragma unroll
  for (int j = 0; j < 8; ++j) {  // fold 1/sqrt(HD) and log2e into Q
    qf[0][j] = (bf16_t)((float)qf[0][j] * kQscale);
    qf[1][j] = (bf16_t)((float)qf[1][j] * kQscale);
  }
  __syncthreads();  // everyone done reading Qs before Ps may overwrite

  const int krow = tid >> 1, kc4 = (tid & 1) * 32;  // K staging
  const int vrg = tid >> 3, vdg = tid & 7;          // V staging (4 rows x 8 d)
  uint4 kr[4], vr[4];
  auto LDK = [&](int kt) {
    const uint4* p = reinterpret_cast<const uint4*>(qkv + (rowbase + kt * 128 + krow) * 3072 + kcol + kc4);
    kr[0] = p[0]; kr[1] = p[1]; kr[2] = p[2]; kr[3] = p[3];
  };
  auto LDV = [&](int kt) {
#pragma unroll
    for (int j2 = 0; j2 < 4; ++j2)
      vr[j2] = *reinterpret_cast<const uint4*>(
          qkv + (rowbase + kt * 128 + vrg * 4 + j2) * 3072 + vcol + vdg * 8);
  };
  auto STK = [&]() {
    *reinterpret_cast<uint4*>(&Ks[krow][kc4]) = kr[0];
    *reinterpret_cast<uint4*>(&Ks[krow][kc4 + 8]) = kr[1];
    *reinterpret_cast<uint4*>(&Ks[krow][kc4 + 16]) = kr[2];
    *reinterpret_cast<uint4*>(&Ks[krow][kc4 + 24]) = kr[3];
  };

  float mrow[4] = {-1e30f, -1e30f, -1e30f, -1e30f};
  float lsum[4] = {0.f, 0.f, 0.f, 0.f}, ssum[4] = {0.f, 0.f, 0.f, 0.f};

  // ---- pass 1: running max / sumexp / sum p*s' (s' = log2-domain score) ----
  LDK(0);
  for (int kt = 0; kt < 16; ++kt) {
    __syncthreads();
    STK();
    __syncthreads();
    if (kt + 1 < 16) LDK(kt + 1);
    f32x4 sc[8] = {};
    __builtin_amdgcn_s_setprio(1);
#pragma unroll
    for (int ds = 0; ds < 2; ++ds)
#pragma unroll
      for (int kf = 0; kf < 8; ++kf) {
        bf16x8 bk = *reinterpret_cast<const bf16x8*>(&Ks[kf * 16 + lrow][ds * 32 + lk8]);
        sc[kf] = mfma16(qf[ds], bk, sc[kf]);
      }
    __builtin_amdgcn_s_setprio(0);
    float tm[4] = {-1e30f, -1e30f, -1e30f, -1e30f};
#pragma unroll
    for (int kf = 0; kf < 8; ++kf)
#pragma unroll
      for (int r = 0; r < 4; ++r) tm[r] = fmaxf(tm[r], sc[kf][r]);
#pragma unroll
    for (int mk = 1; mk < 16; mk <<= 1)
#pragma unroll
      for (int r = 0; r < 4; ++r) tm[r] = fmaxf(tm[r], __shfl_xor(tm[r], mk));
#pragma unroll
    for (int r = 0; r < 4; ++r) {
      const float mn = fmaxf(mrow[r], tm[r]);
      const float f = ex2(mrow[r] - mn);
      lsum[r] *= f;
      ssum[r] *= f;
      mrow[r] = mn;
    }
#pragma unroll
    for (int kf = 0; kf < 8; ++kf)
#pragma unroll
      for (int r = 0; r < 4; ++r) {
        const float p = ex2(sc[kf][r] - mrow[r]);
        lsum[r] += p;
        ssum[r] += p * sc[kf][r];
      }
  }
#pragma unroll
  for (int mk = 1; mk < 16; mk <<= 1)
#pragma unroll
    for (int r = 0; r < 4; ++r) {
      lsum[r] += __shfl_xor(lsum[r], mk);
      ssum[r] += __shfl_xor(ssum[r], mk);
    }
  float linv[4];
#pragma unroll
  for (int r = 0; r < 4; ++r) linv[r] = 1.0f / lsum[r];
  if (lrow == 0) {  // entropy = log2(l) - (E[s'] - m')   (log2 domain)
#pragma unroll
    for (int r = 0; r < 4; ++r) {
      const float Hent = lg2(lsum[r]) - (ssum[r] * linv[r] - mrow[r]);
      entO[(long)(h * kB + b) * kS + q0 + wv * 16 + (ln >> 4) * 4 + r] = Hent;
    }
  }

  // ---- pass 2: recompute scores, emit attn weights, accumulate PV ----
  f32x4 accO[4] = {};
  LDK(0);
  LDV(0);
  for (int kt = 0; kt < 16; ++kt) {
    __syncthreads();
    STK();
    {  // V transpose: pack 4 k-rows per d -> ds_write_b64 (8 per thread)
#pragma unroll
      for (int j = 0; j < 8; ++j) {
        us4 pk;
        pk[0] = reinterpret_cast<const ushort*>(&vr[0])[j];
        pk[1] = reinterpret_cast<const ushort*>(&vr[1])[j];
        pk[2] = reinterpret_cast<const ushort*>(&vr[2])[j];
        pk[3] = reinterpret_cast<const ushort*>(&vr[3])[j];
        *reinterpret_cast<us4*>(&Vts[vdg * 8 + j][vrg * 4]) = pk;
      }
    }
    __syncthreads();
    if (kt + 1 < 16) { LDK(kt + 1); LDV(kt + 1); }
    f32x4 sc[8] = {};
    __builtin_amdgcn_s_setprio(1);
#pragma unroll
    for (int ds = 0; ds < 2; ++ds)
#pragma unroll
      for (int kf = 0; kf < 8; ++kf) {
        bf16x8 bk = *reinterpret_cast<const bf16x8*>(&Ks[kf * 16 + lrow][ds * 32 + lk8]);
        sc[kf] = mfma16(qf[ds], bk, sc[kf]);
      }
    __builtin_amdgcn_s_setprio(0);
    const long arow0 = (long)(h * kB + b) * kS + q0 + wv * 16;
#pragma unroll
    for (int kf = 0; kf < 8; ++kf)
#pragma unroll
      for (int r = 0; r < 4; ++r) {
        const int qr = (ln >> 4) * 4 + r;
        const float p = ex2(sc[kf][r] - mrow[r]) * linv[r];
        __builtin_nontemporal_store(p, &attnO[(arow0 + qr) * (long)kS + kt * 128 + kf * 16 + lrow]);
        QP.Ps[wv][qr][kf * 16 + lrow] = (bf16_t)p;
      }
    // No barrier: Ps[wv] is wave-private (compiler orders via lgkmcnt).
    __builtin_amdgcn_s_setprio(1);
#pragma unroll
    for (int ks = 0; ks < 4; ++ks) {
      bf16x8 pfr = *reinterpret_cast<const bf16x8*>(&QP.Ps[wv][lrow][ks * 32 + lk8]);
#pragma unroll
      for (int df = 0; df < 4; ++df) {
        bf16x8 vfr = *reinterpret_cast<const bf16x8*>(&Vts[df * 16 + lrow][ks * 32 + lk8]);
        accO[df] = mfma16(pfr, vfr, accO[df]);
      }
    }
    __builtin_amdgcn_s_setprio(0);
  }
  // y = concat(head_out) + x
#pragma unroll
  for (int df = 0; df < 4; ++df)
#pragma unroll
    for (int r = 0; r < 4; ++r) {
      const long row = rowbase + q0 + wv * 16 + (ln >> 4) * 4 + r;
      const int col = h * 64 + df * 16 + lrow;
      y[row * kD + col] = accO[df][r] + x[row * kD + col];
    }
}

extern "C" void kernel_launch(void* const* d_in, const int* in_sizes, int n_in,
                              void* d_out, int out_size, void* d_ws, size_t ws_size,
                              hipStream_t stream) {
  const float* x    = (const float*)d_in[0];
  const float* Wq   = (const float*)d_in[1];
  const float* bq   = (const float*)d_in[2];
  const float* Wk   = (const float*)d_in[3];
  const float* bk   = (const float*)d_in[4];
  const float* Wv   = (const float*)d_in[5];
  const float* bv   = (const float*)d_in[6];
  const float* ln1g = (const float*)d_in[7];
  const float* ln1b = (const float*)d_in[8];
  const float* ln2g = (const float*)d_in[9];
  const float* ln2b = (const float*)d_in[10];
  const float* W1   = (const float*)d_in[11];
  const float* b1   = (const float*)d_in[12];
  const float* W2   = (const float*)d_in[13];
  const float* b2   = (const float*)d_in[14];

  float* outMain = (float*)d_out;                       // [2,2048,1024]
  float* attnO   = outMain + (long)kRows * kD;          // [16,2,2048,2048]
  float* entO    = attnO + (long)kH * kB * kS * kS;     // [16,2,2048]

  // Scratch plan (peak d_ws = 62 MB): h1/h2 live in d_out's outMain region
  // (dead before MLP2 fully overwrites it); mid aliases dead qkv in d_ws.
  bf16_t* h1 = (bf16_t*)outMain;                           // 8 MB scratch in d_out
  bf16_t* h2 = (bf16_t*)(outMain + (long)kRows * kD / 2);  // second 8 MB half

  char* ws = (char*)d_ws;
  bf16_t* wqkvt = (bf16_t*)ws; ws += (long)3072 * 1024 * 2;   //  6 MB (persist)
  bf16_t* w1t   = (bf16_t*)ws; ws += (long)4096 * 1024 * 2;   //  8 MB (persist)
  bf16_t* w2t   = (bf16_t*)ws; ws += (long)1024 * 4096 * 2;   //  8 MB (persist)
  float*  yb    = (float*)ws;  ws += (long)kRows * kD * 4;    // 16 MB (persist attn->MLP2)
  char* regionA = ws;                                         // 32 MB shared region
  bf16_t* qkv   = (bf16_t*)regionA;                           // 24 MB (dead after attn)
  bf16_t* mid   = (bf16_t*)regionA;                           // 32 MB (aliases qkv)

  // weight conversion/transpose to bf16 [N][K]
  hipLaunchKernelGGL(k_transpose, dim3(16, 1, 16), dim3(256), 0, stream, Wq, wqkvt,             1024, 64, (long)65536, (long)65536);
  hipLaunchKernelGGL(k_transpose, dim3(16, 1, 16), dim3(256), 0, stream, Wk, wqkvt + 1024*1024, 1024, 64, (long)65536, (long)65536);
  hipLaunchKernelGGL(k_transpose, dim3(16, 1, 16), dim3(256), 0, stream, Wv, wqkvt + 2048*1024, 1024, 64, (long)65536, (long)65536);
  hipLaunchKernelGGL(k_transpose, dim3(16, 64, 1), dim3(256), 0, stream, W1, w1t, 1024, 4096, 0L, 0L);
  hipLaunchKernelGGL(k_transpose, dim3(64, 16, 1), dim3(256), 0, stream, W2, w2t, 4096, 1024, 0L, 0L);
  // LN1
  hipLaunchKernelGGL(k_ln, dim3(kRows / 4), dim3(256), 0, stream, x, ln1g, ln1b, h1);
  // fused QKV projection
  hipLaunchKernelGGL((k_gemm<128, 128, 64, 64, 0>), dim3(3072 / 128, kRows / 128), dim3(256), 0, stream,
                     h1, wqkvt, nullptr, qkv, bq, bk, bv, nullptr, kRows, 3072, 1024);
  // attention (+ attn weights, entropy, y = cat + x)
  hipLaunchKernelGGL(k_attn, dim3(kS / 64, kH, kB), dim3(256), 0, stream, qkv, x, attnO, entO, yb);
  // LN2
  hipLaunchKernelGGL(k_ln, dim3(kRows / 4), dim3(256), 0, stream, yb, ln2g, ln2b, h2);
  // MLP
  hipLaunchKernelGGL((k_gemm<128, 128, 64, 64, 1>), dim3(kDff / 128, kRows / 128), dim3(256), 0, stream,
                     h2, w1t, nullptr, mid, b1, nullptr, nullptr, nullptr, kRows, kDff, 1024);
  hipLaunchKernelGGL((k_gemm<64, 128, 32, 64, 2>), dim3(kD / 128, kRows / 64), dim3(256), 0, stream,
                     mid, w2t, outMain, nullptr, b2, nullptr, nullptr, yb, kRows, kD, 4096);
}